// Round 6
// baseline (149.649 us; speedup 1.0000x reference)
//
#include <hip/hip_runtime.h>
#include <hip/hip_cooperative_groups.h>
#include <math.h>
#include <stdint.h>

namespace cg = cooperative_groups;

#define B_ 16
#define L_ 50
#define LU_ 60
#define KU_ 100
#define DIM_ 60
#define V_ 2000
#define MAXVL_ 10
#define MIN_WL_ 4
#define MAX_WL_ 10
#define NE_ 7            // MAX_WL - MIN_WL + 1
#define IDC_ 3.5f
#define LOG_UNEXT_ (-4.6051701859880913680359829093687f)  // log(0.01)
#define CTXW_ 0.1f
#define NQ_ 13           // l-quads per batch row (13*4 >= 50)
#define NT_ 512          // threads per block (8 waves)

// workspace layout (bytes)
#define WS_PLP  0                  // pos_lp(+2*IDC): B*L*KU = 80000 floats
#define WS_BEST_BYTES (80000u * 4u)       // 320000: 16 padded u64 slots
#define BEST_STRIDE 8              // 64 B between per-batch atomic slots
#define WS_CNT_OFF   (WS_BEST_BYTES + 1024u)   // 16 u32 counters, 64B-strided
#define CNT_STRIDE 16              // dwords between per-b counters
#define WS_VPACK_BYTES (WS_BEST_BYTES + 2048u) // 2000 int4, 16B aligned

#define URP_ 61   // padded LDS stride (odd -> conflict-free strided reads)
#define CWP_ 61

// DP tile: pair rows (r, r+5) as float2, stride S2_ dwords (lane-to-bank
// step 202%32=10 -> 4 dwords/bank per b64 read = minimum bank cycles).
#define S2_ 202
#define NKEY_ 54  // keys 0..53 (lane<=49, r2<=4)

struct CtxS {
  float s_ur[KU_ * URP_];       // unit_repr padded (24400 B)
  float s_cw[3 * DIM_ * CWP_];  // conv_w transposed (43920 B)
  float s_aw[7 * KU_];
  float s_kx[7 * DIM_];
  float swr[4 * DIM_];
  float sclp[4 * KU_];
  float sctx[4 * KU_];
  float salg[KU_];
  float sls[9];
};
struct DpS {
  float sp[NKEY_ * S2_];        // 43632 B
  unsigned long long swave[8];
};
union SU { CtxS c; DpS d; };    // 77.4 KB max -> 1 block/CU co-resident

// -------------------------------------------------------------------------
__device__ __forceinline__ void pack_one(int v,
    const int* __restrict__ vocab_ids, const int* __restrict__ vocab_lengths,
    int* __restrict__ vpack)
{
  int vl = vocab_lengths[v];
  unsigned q0 = 0u, q1 = 0u, q2 = 0u;
#pragma unroll
  for (int j = 0; j < 4; ++j) q0 |= ((unsigned)vocab_ids[v * MAXVL_ + j]) << (j * 8);
#pragma unroll
  for (int j = 0; j < 4; ++j) q1 |= ((unsigned)vocab_ids[v * MAXVL_ + 4 + j]) << (j * 8);
#pragma unroll
  for (int j = 0; j < 2; ++j) q2 |= ((unsigned)vocab_ids[v * MAXVL_ + 8 + j]) << (j * 8);
  int4 w;
  w.x = (int)q0; w.y = (int)q1; w.z = (int)q2;
  w.w = (int)((unsigned)vl | ((unsigned)v << 8));
  ((int4*)vpack)[v] = w;
}

// -------------------------------------------------------------------------
// ctx tile for one (b, l-quad), 512 threads. ws_plp gets pos_lp + 2*IDC
// (potential-transformed DP operand). Proven body (r3-r5), strides -> 512.
__device__ void ctx_tile_dev(CtxS& S, int blk, int t,
    const int* __restrict__ uid, const float* __restrict__ unit_repr,
    const float* __restrict__ aligner_w, const float* __restrict__ conv_w,
    const float* __restrict__ conv_b, float* __restrict__ ws_plp,
    float* __restrict__ out_align)
{
  int b = blk / NQ_, q = blk % NQ_;
  int l0 = 4 * q;
  int npos = (l0 + 4 <= L_) ? 4 : (L_ - l0);
  int alr = (blk < LU_) ? blk : -1;

  // --- P0: stage weights (float4 global) + aligner rows
  const float4* ur4 = (const float4*)unit_repr;
  for (int k = t; k < (KU_ * DIM_) / 4; k += NT_) {
    float4 v = ur4[k];
    int i0 = 4 * k;
    S.s_ur[((i0 + 0) / DIM_) * URP_ + ((i0 + 0) % DIM_)] = v.x;
    S.s_ur[((i0 + 1) / DIM_) * URP_ + ((i0 + 1) % DIM_)] = v.y;
    S.s_ur[((i0 + 2) / DIM_) * URP_ + ((i0 + 2) % DIM_)] = v.z;
    S.s_ur[((i0 + 3) / DIM_) * URP_ + ((i0 + 3) % DIM_)] = v.w;
  }
  const float4* cw4 = (const float4*)conv_w;
  for (int k = t; k < (DIM_ * DIM_ * 3) / 4; k += NT_) {
    float4 v = cw4[k];
    int i0 = 4 * k;
    float vv[4] = {v.x, v.y, v.z, v.w};
#pragma unroll
    for (int e = 0; e < 4; ++e) {
      int idx = i0 + e;
      int o = idx / (3 * DIM_), id = idx % (3 * DIM_);
      S.s_cw[id * CWP_ + o] = vv[e];
    }
  }
  for (int i = t; i < 7 * KU_; i += NT_) {
    int m = i / KU_, k = i - m * KU_;
    float w = 0.f;
    if (m < 6) {
      int ld = l0 - 1 + m;
      if (ld >= 0 && ld < L_) {
        int u = uid[b * L_ + ld];
        w = aligner_w[u * KU_ + k];
      }
    } else if (alr >= 0) {
      w = aligner_w[alr * KU_ + k];
    }
    S.s_aw[i] = w;
  }
  __syncthreads();

  // --- P1: ku rows (420 outputs, 100 MACs)
  for (int idx = t; idx < 7 * DIM_; idx += NT_) {
    int m = idx / DIM_, c = idx - m * DIM_;
    const float4* aw4 = (const float4*)&S.s_aw[m * KU_];
    float acc = 0.f;
    for (int k4 = 0; k4 < KU_ / 4; ++k4) {
      float4 a = aw4[k4];
      int k = 4 * k4;
      acc += a.x * S.s_ur[(k + 0) * URP_ + c];
      acc += a.y * S.s_ur[(k + 1) * URP_ + c];
      acc += a.z * S.s_ur[(k + 2) * URP_ + c];
      acc += a.w * S.s_ur[(k + 3) * URP_ + c];
    }
    S.s_kx[idx] = acc;
  }
  __syncthreads();

  // --- P2: conv (240) + char logits (400)
  for (int idx = t; idx < 240 + 4 * KU_; idx += NT_) {
    if (idx < 240) {
      int p = idx / DIM_, o = idx - p * DIM_;
      const float4* x04 = (const float4*)&S.s_kx[(p + 0) * DIM_];
      const float4* x14 = (const float4*)&S.s_kx[(p + 1) * DIM_];
      const float4* x24 = (const float4*)&S.s_kx[(p + 2) * DIM_];
      float acc = conv_b[o];
      for (int i4 = 0; i4 < DIM_ / 4; ++i4) {
        float4 x0 = x04[i4], x1 = x14[i4], x2 = x24[i4];
        int i = 4 * i4;
        acc += x0.x * S.s_cw[((i + 0) * 3 + 0) * CWP_ + o];
        acc += x1.x * S.s_cw[((i + 0) * 3 + 1) * CWP_ + o];
        acc += x2.x * S.s_cw[((i + 0) * 3 + 2) * CWP_ + o];
        acc += x0.y * S.s_cw[((i + 1) * 3 + 0) * CWP_ + o];
        acc += x1.y * S.s_cw[((i + 1) * 3 + 1) * CWP_ + o];
        acc += x2.y * S.s_cw[((i + 1) * 3 + 2) * CWP_ + o];
        acc += x0.z * S.s_cw[((i + 2) * 3 + 0) * CWP_ + o];
        acc += x1.z * S.s_cw[((i + 2) * 3 + 1) * CWP_ + o];
        acc += x2.z * S.s_cw[((i + 2) * 3 + 2) * CWP_ + o];
        acc += x0.w * S.s_cw[((i + 3) * 3 + 0) * CWP_ + o];
        acc += x1.w * S.s_cw[((i + 3) * 3 + 1) * CWP_ + o];
        acc += x2.w * S.s_cw[((i + 3) * 3 + 2) * CWP_ + o];
      }
      S.swr[p * DIM_ + o] = acc;
    } else {
      int r = idx - 240;
      int p = r / KU_, j = r - p * KU_;
      const float4* kx4 = (const float4*)&S.s_kx[(p + 1) * DIM_];
      float acc = 0.f;
      for (int d4 = 0; d4 < DIM_ / 4; ++d4) {
        float4 x = kx4[d4];
        int d = 4 * d4;
        acc += x.x * S.s_ur[j * URP_ + d + 0];
        acc += x.y * S.s_ur[j * URP_ + d + 1];
        acc += x.z * S.s_ur[j * URP_ + d + 2];
        acc += x.w * S.s_ur[j * URP_ + d + 3];
      }
      S.sclp[r] = acc;
    }
  }
  __syncthreads();

  // --- P3: ctx logits (400) + align logits (100)
  for (int idx = t; idx < 4 * KU_ + KU_; idx += NT_) {
    if (idx < 4 * KU_) {
      int p = idx / KU_, j = idx - p * KU_;
      const float4* w4 = (const float4*)&S.swr[p * DIM_];
      float acc = 0.f;
      for (int d4 = 0; d4 < DIM_ / 4; ++d4) {
        float4 x = w4[d4];
        int d = 4 * d4;
        acc += x.x * S.s_ur[j * URP_ + d + 0];
        acc += x.y * S.s_ur[j * URP_ + d + 1];
        acc += x.z * S.s_ur[j * URP_ + d + 2];
        acc += x.w * S.s_ur[j * URP_ + d + 3];
      }
      S.sctx[idx] = acc;
    } else {
      int j = idx - 4 * KU_;
      const float4* kx4 = (const float4*)&S.s_kx[6 * DIM_];
      float acc = 0.f;
      for (int d4 = 0; d4 < DIM_ / 4; ++d4) {
        float4 x = kx4[d4];
        int d = 4 * d4;
        acc += x.x * S.s_ur[j * URP_ + d + 0];
        acc += x.y * S.s_ur[j * URP_ + d + 1];
        acc += x.z * S.s_ur[j * URP_ + d + 2];
        acc += x.w * S.s_ur[j * URP_ + d + 3];
      }
      S.salg[j] = acc;
    }
  }
  __syncthreads();

  // --- P4: 9 logsumexp reductions (16 groups of 32 lanes, 9 active)
  {
    int g = t >> 5, lane = t & 31;
    if (g < 9) {
      const float* arr = (g == 8) ? S.salg
                        : ((g & 1) ? &S.sctx[(g >> 1) * KU_] : &S.sclp[(g >> 1) * KU_]);
      float v1 = arr[lane];
      float v2 = arr[32 + lane];
      float v3 = arr[64 + lane];
      float v4 = (lane < KU_ - 96) ? arr[96 + lane] : -1e30f;
      float mx = fmaxf(fmaxf(v1, v2), fmaxf(v3, v4));
#pragma unroll
      for (int off = 16; off > 0; off >>= 1)
        mx = fmaxf(mx, __shfl_xor(mx, off));
      float s = expf(v1 - mx) + expf(v2 - mx) + expf(v3 - mx) +
                ((lane < KU_ - 96) ? expf(v4 - mx) : 0.f);
#pragma unroll
      for (int off = 16; off > 0; off >>= 1)
        s += __shfl_xor(s, off);
      if (lane == 0) S.sls[g] = mx + logf(s);
    }
  }
  __syncthreads();

  // --- P5: guarded outputs
  for (int idx = t; idx < 4 * KU_; idx += NT_) {
    int p = idx / KU_, j = idx - p * KU_;
    if (p < npos) {
      float pos = (S.sclp[idx] - S.sls[2 * p]) + CTXW_ * (S.sctx[idx] - S.sls[2 * p + 1]);
      ws_plp[(b * L_ + l0 + p) * KU_ + j] = pos + 2.0f * IDC_;
    }
  }
  if (alr >= 0 && t < KU_)
    out_align[alr * KU_ + t] = expf(S.salg[t] - S.sls[8]);
}

// -------------------------------------------------------------------------
// DP core for one wave-uniform vocab of length VL (proven r4/r5).
template<int VL>
__device__ __forceinline__ unsigned long long dp_one(
    const float* __restrict__ fb,
    unsigned q0, unsigned q1, unsigned q2,
    const float* cvec, int lbase, int vid)
{
  float D[MAXVL_ + 1];
#pragma unroll
  for (int i = 0; i <= MAXVL_; ++i) D[i] = 0.f;

#pragma unroll
  for (int j = 0; j < VL; ++j) {
    unsigned qq = (j < 4) ? q0 : ((j < 8) ? q1 : q2);
    int k2 = (int)((qq >> ((j & 3) * 8)) & 0xFFu) * 2;   // dword offset (scalar)
    float2 p0 = *(const float2*)(fb + k2);
    float2 p1 = *(const float2*)(fb + k2 + S2_);
    float2 p2 = *(const float2*)(fb + k2 + 2 * S2_);
    float2 p3 = *(const float2*)(fb + k2 + 3 * S2_);
    float2 p4 = *(const float2*)(fb + k2 + 4 * S2_);
    float s[MAXVL_] = {p0.x, p1.x, p2.x, p3.x, p4.x,
                       p0.y, p1.y, p2.y, p3.y, p4.y};
    float left = 0.f;
#pragma unroll
    for (int i = 1; i <= MAXVL_; ++i) {
      float nv = fmaxf(D[i - 1] + s[i - 1], fmaxf(D[i], left));  // add + max3
      D[i - 1] = left;
      left = nv;
    }
    D[MAXVL_] = left;
  }

  float bestSc = -1e30f;
  int bestEV = 0;
#pragma unroll
  for (int e = 0; e < NE_; ++e) {
    float sc = D[MIN_WL_ + e] + cvec[e];     // cvec masks non-viable (i,lane)
    if (sc > bestSc) { bestSc = sc; bestEV = e * V_; }
  }
  bestSc -= IDC_ * (float)VL;
  unsigned idx = (unsigned)(lbase + bestEV + vid);
  unsigned u = __float_as_uint(bestSc);
  u = (u & 0x80000000u) ? ~u : (u | 0x80000000u);
  unsigned long long key =
      ((unsigned long long)u << 32) | (unsigned long long)(~idx);
  return (bestSc > -1e29f) ? key : 0ull;
}

// -------------------------------------------------------------------------
// DP phase for one (b, vocab-chunk-of-125) unit, 512 threads (8 waves).
// Stages the b-tile once; each wave runs ~16 wave-uniform vocabs with
// prefetched vpack loads; decode fused via per-b counters (16 arrivals).
__device__ void dp_dev(DpS& D, int b, int c, int t,
    const int* __restrict__ lengths, const float* __restrict__ ws_plp,
    const int* __restrict__ vpack, unsigned long long* __restrict__ g_best,
    unsigned* __restrict__ cnt, float* __restrict__ out)
{
  int len_b = lengths[b];

  const float4* src4 = (const float4*)ws_plp;
  for (int idx = t; idx < NKEY_ * 25; idx += NT_) {
    int key = idx / 25, m = idx - key * 25;
    int ra = b * L_ + key;     if (ra > B_ * L_ - 1) ra = B_ * L_ - 1;
    int rb = b * L_ + key + 5; if (rb > B_ * L_ - 1) rb = B_ * L_ - 1;
    float4 qa = src4[ra * 25 + m];
    float4 qb = src4[rb * 25 + m];
    float2* dst = (float2*)&D.sp[key * S2_ + 8 * m];
    dst[0] = make_float2(qa.x, qb.x);
    dst[1] = make_float2(qa.y, qb.y);
    dst[2] = make_float2(qa.z, qb.z);
    dst[3] = make_float2(qa.w, qb.w);
  }

  int lane = t & 63, w = t >> 6;
  float cvec[NE_];
#pragma unroll
  for (int e = 0; e < NE_; ++e) {
    int i = MIN_WL_ + e;
    bool ok = (lane < L_) && (i <= len_b - lane);
    cvec[e] = ok ? ((float)(len_b - i) * LOG_UNEXT_ - IDC_ * (float)i) : -1e30f;
  }
  int lbase = lane * (NE_ * V_);
  int lcl = (lane < L_) ? lane : (L_ - 1);
  const float* fb = D.sp + lcl * S2_;
  __syncthreads();

  unsigned long long bestKey = 0ull;
  const int4* vp4 = (const int4*)vpack;
  int vbase = c * 125;
  int4 wq = (w < 125) ? vp4[vbase + w] : make_int4(0, 0, 0, 0);
#pragma unroll 1
  for (int n = 0; n < 16; ++n) {
    int vln = w + 8 * (n + 1);
    int4 wqn = (vln < 125) ? vp4[vbase + vln] : make_int4(0, 0, 0, 0);
    if (w + 8 * n < 125) {            // wave-uniform guard
      unsigned q0 = (unsigned)__builtin_amdgcn_readfirstlane(wq.x);
      unsigned q1 = (unsigned)__builtin_amdgcn_readfirstlane(wq.y);
      unsigned q2 = (unsigned)__builtin_amdgcn_readfirstlane(wq.z);
      unsigned q3 = (unsigned)__builtin_amdgcn_readfirstlane(wq.w);
      int vlen = (int)(q3 & 0xFFu);
      int vid = (int)(q3 >> 8);
      unsigned long long kk = 0ull;
      switch (vlen) {                 // uniform scalar branch
        case 4:  kk = dp_one<4>(fb, q0, q1, q2, cvec, lbase, vid); break;
        case 5:  kk = dp_one<5>(fb, q0, q1, q2, cvec, lbase, vid); break;
        case 6:  kk = dp_one<6>(fb, q0, q1, q2, cvec, lbase, vid); break;
        case 7:  kk = dp_one<7>(fb, q0, q1, q2, cvec, lbase, vid); break;
        case 8:  kk = dp_one<8>(fb, q0, q1, q2, cvec, lbase, vid); break;
        case 9:  kk = dp_one<9>(fb, q0, q1, q2, cvec, lbase, vid); break;
        case 10: kk = dp_one<10>(fb, q0, q1, q2, cvec, lbase, vid); break;
        default: break;
      }
      if (kk > bestKey) bestKey = kk;
    }
    wq = wqn;
  }

#pragma unroll
  for (int off = 32; off > 0; off >>= 1) {
    unsigned long long o = __shfl_down(bestKey, off);
    if (o > bestKey) bestKey = o;
  }
  if ((t & 63) == 0) D.swave[w] = bestKey;
  __syncthreads();
  if (t == 0) {
    unsigned long long k0 = D.swave[0];
    for (int x = 1; x < 8; ++x)
      if (D.swave[x] > k0) k0 = D.swave[x];
    unsigned long long old = atomicMax(g_best + (size_t)b * BEST_STRIDE, k0);
    asm volatile("" :: "v"(old));     // consume: RMW complete before counter
    unsigned prev = atomicAdd(&cnt[b * CNT_STRIDE], 1u);
    if (prev == 15u) {
      // last of 16 chunks for this b: decode (atomic RMW = coherence point)
      unsigned long long key = atomicMax(g_best + (size_t)b * BEST_STRIDE, 0ull);
      unsigned int u = (unsigned int)(key >> 32);
      unsigned int idx = ~((unsigned int)(key & 0xFFFFFFFFull));
      unsigned int bits = (u & 0x80000000u) ? (u & 0x7FFFFFFFu) : ~u;
      float val = __uint_as_float(bits);
      int start = (int)(idx / (NE_ * V_));
      int rem = (int)(idx % (NE_ * V_));
      int e = rem / V_;
      int vv = rem % V_;
      out[b] = (float)start;
      out[B_ + b] = (float)(start + MIN_WL_ + e - 1);
      out[2 * B_ + b] = val;
      out[3 * B_ + b] = (float)vv;
    }
  }
}

// -------------------------------------------------------------------------
// Phase A body (shared by mega and fallback k_ctx).
__device__ __forceinline__ void phaseA(SU& su, int blk, int t,
    const int* uid, const float* unit_repr, const float* aligner_w,
    const float* conv_w, const float* conv_b, const int* vocab_ids,
    const int* vocab_lengths, float* ws_plp, float* out_align,
    unsigned long long* g_best, unsigned* cnt, int* vpack)
{
  if (blk < B_ * NQ_) {
    ctx_tile_dev(su.c, blk, t, uid, unit_repr, aligner_w, conv_w, conv_b,
                 ws_plp, out_align);
  } else {
    int v = (blk - B_ * NQ_) * NT_ + t;   // blocks 208..211 cover 0..2047
    if (v < V_) pack_one(v, vocab_ids, vocab_lengths, vpack);
    if (blk == 255) {
      if (t < B_) g_best[t * BEST_STRIDE] = 0ull;
      if (t >= 64 && t < 64 + B_) cnt[(t - 64) * CNT_STRIDE] = 0u;
    }
  }
}

// -------------------------------------------------------------------------
// Single cooperative kernel: phase A -> grid.sync -> DP + fused decode.
__global__ __launch_bounds__(NT_) void mega_kernel(
    const int* __restrict__ uid, const int* __restrict__ lengths,
    const float* __restrict__ unit_repr, const float* __restrict__ aligner_w,
    const float* __restrict__ conv_w, const float* __restrict__ conv_b,
    const int* __restrict__ vocab_ids, const int* __restrict__ vocab_lengths,
    float* __restrict__ ws_plp, float* __restrict__ out_align,
    unsigned long long* __restrict__ g_best, unsigned* __restrict__ cnt,
    int* __restrict__ vpack, float* __restrict__ out)
{
  __shared__ SU su;
  int blk = blockIdx.x, t = threadIdx.x;
  phaseA(su, blk, t, uid, unit_repr, aligner_w, conv_w, conv_b,
         vocab_ids, vocab_lengths, ws_plp, out_align, g_best, cnt, vpack);
  cg::this_grid().sync();               // device-scope fence + grid barrier
  dp_dev(su.d, blk >> 4, blk & 15, t, lengths, ws_plp, vpack, g_best, cnt, out);
}

// Fallback (non-cooperative): two ordinary dispatches, same device code.
__global__ __launch_bounds__(NT_) void k_ctx(
    const int* __restrict__ uid, const float* __restrict__ unit_repr,
    const float* __restrict__ aligner_w, const float* __restrict__ conv_w,
    const float* __restrict__ conv_b, const int* __restrict__ vocab_ids,
    const int* __restrict__ vocab_lengths, float* __restrict__ ws_plp,
    float* __restrict__ out_align, unsigned long long* __restrict__ g_best,
    unsigned* __restrict__ cnt, int* __restrict__ vpack)
{
  __shared__ SU su;
  phaseA(su, blockIdx.x, threadIdx.x, uid, unit_repr, aligner_w, conv_w,
         conv_b, vocab_ids, vocab_lengths, ws_plp, out_align, g_best, cnt,
         vpack);
}

__global__ __launch_bounds__(NT_) void k_dp(
    const int* __restrict__ lengths, const float* __restrict__ ws_plp,
    const int* __restrict__ vpack, unsigned long long* __restrict__ g_best,
    unsigned* __restrict__ cnt, float* __restrict__ out)
{
  __shared__ DpS d;
  dp_dev(d, blockIdx.x >> 4, blockIdx.x & 15, threadIdx.x,
         lengths, ws_plp, vpack, g_best, cnt, out);
}

// -------------------------------------------------------------------------
extern "C" void kernel_launch(void* const* d_in, const int* in_sizes, int n_in,
                              void* d_out, int out_size, void* d_ws, size_t ws_size,
                              hipStream_t stream)
{
  const int* uid            = (const int*)d_in[0];
  const int* lengths        = (const int*)d_in[1];
  const float* unit_repr    = (const float*)d_in[2];
  const float* aligner_w    = (const float*)d_in[3];
  const float* conv_w       = (const float*)d_in[4];
  const float* conv_b       = (const float*)d_in[5];
  const int* vocab_ids      = (const int*)d_in[6];
  const int* vocab_lengths  = (const int*)d_in[7];
  float* out = (float*)d_out;
  float* out_align = out + 4 * B_;
  float* ws_plp = (float*)d_ws;
  unsigned long long* g_best =
      (unsigned long long*)((char*)d_ws + WS_BEST_BYTES);
  unsigned* cnt = (unsigned*)((char*)d_ws + WS_CNT_OFF);
  int* vpack = (int*)((char*)d_ws + WS_VPACK_BYTES);

  void* args[] = {
    (void*)&uid, (void*)&lengths, (void*)&unit_repr, (void*)&aligner_w,
    (void*)&conv_w, (void*)&conv_b, (void*)&vocab_ids, (void*)&vocab_lengths,
    (void*)&ws_plp, (void*)&out_align, (void*)&g_best, (void*)&cnt,
    (void*)&vpack, (void*)&out
  };
  hipError_t e = hipLaunchCooperativeKernel((const void*)mega_kernel,
                                            dim3(256), dim3(NT_), args, 0,
                                            stream);
  if (e != hipSuccess) {
    // fallback: two ordinary dispatches (kernel boundary = device fence)
    k_ctx<<<256, NT_, 0, stream>>>(uid, unit_repr, aligner_w, conv_w, conv_b,
                                   vocab_ids, vocab_lengths, ws_plp,
                                   out_align, g_best, cnt, vpack);
    k_dp<<<256, NT_, 0, stream>>>(lengths, ws_plp, vpack, g_best, cnt, out);
  }
}

// Round 7
// 100.028 us; speedup vs baseline: 1.4961x; 1.4961x over previous
//
#include <hip/hip_runtime.h>
#include <math.h>
#include <stdint.h>

#define B_ 16
#define L_ 50
#define LU_ 60
#define KU_ 100
#define DIM_ 60
#define V_ 2000
#define MAXVL_ 10
#define MIN_WL_ 4
#define MAX_WL_ 10
#define NE_ 7            // MAX_WL - MIN_WL + 1
#define IDC_ 3.5f
#define LOG_UNEXT_ (-4.6051701859880913680359829093687f)  // log(0.01)
#define CTXW_ 0.1f
#define NQ_ 13           // l-quads per batch row (13*4 >= 50)

// workspace layout (bytes)
#define WS_PLP  0                  // pos_lp(+2*IDC): B*L*KU = 80000 floats
#define WS_BEST_BYTES (80000u * 4u)       // 320000: 16 padded u64 slots
#define BEST_STRIDE 8              // 64 B between per-batch atomic slots
#define WS_VPACK_BYTES (WS_BEST_BYTES + 1024u)  // 321024 (16B aligned): 2000 int4

#define URP_ 61   // padded LDS stride (odd -> conflict-free strided reads)
#define CWP_ 61

// dp4 tile: 14 plp rows (l0 .. l0+13) stored as 7 float2 pair-rows
// (rows 2r2, 2r2+1), pair-row stride S2P_ dwords. One b64 per (pair,column).
#define S2P_ 208
#define NROW_ 14

// -------------------------------------------------------------------------
// Kernel 1: fused prep+ctx (208 blocks) + vocab counting-sort (block 208).
// ws_plp stores pos_lp + 2*IDC (potential-transformed DP operand).
// PROVEN body (r3 bench, 101.96us) - unchanged.
__global__ __launch_bounds__(256) void ctx_kernel(
    const int* __restrict__ uid,        // (B, L)
    const float* __restrict__ unit_repr,// (KU, DIM)
    const float* __restrict__ aligner_w,// (LU, KU)
    const float* __restrict__ conv_w,   // (DIM, DIM, 3)
    const float* __restrict__ conv_b,   // (DIM,)
    const int* __restrict__ vocab_ids,  // (V, MAXVL)
    const int* __restrict__ vocab_lengths, // (V,)
    float* __restrict__ ws_plp,         // (B*L, KU)
    float* __restrict__ out_align,      // (LU, KU)
    unsigned long long* __restrict__ g_best,
    int* __restrict__ vpack)            // (V, int4)
{
  int blk = blockIdx.x;
  int t = threadIdx.x;

  // ---- sort block: counting-sort vocab by vlen, pack ids
  if (blk == B_ * NQ_) {
    __shared__ unsigned scnt[NE_];
    if (t < NE_) scnt[t] = 0u;
    __syncthreads();
    for (int v = t; v < V_; v += 256)
      atomicAdd(&scnt[vocab_lengths[v] - MIN_WL_], 1u);
    __syncthreads();
    if (t == 0) {
      unsigned s = 0;
      for (int e = 0; e < NE_; ++e) { unsigned c = scnt[e]; scnt[e] = s; s += c; }
    }
    __syncthreads();
    for (int v = t; v < V_; v += 256) {
      int vl = vocab_lengths[v];
      unsigned dst = atomicAdd(&scnt[vl - MIN_WL_], 1u);
      unsigned q0 = 0u, q1 = 0u, q2 = 0u;
#pragma unroll
      for (int j = 0; j < 4; ++j) q0 |= ((unsigned)vocab_ids[v * MAXVL_ + j]) << (j * 8);
#pragma unroll
      for (int j = 0; j < 4; ++j) q1 |= ((unsigned)vocab_ids[v * MAXVL_ + 4 + j]) << (j * 8);
#pragma unroll
      for (int j = 0; j < 2; ++j) q2 |= ((unsigned)vocab_ids[v * MAXVL_ + 8 + j]) << (j * 8);
      int4 w;
      w.x = (int)q0; w.y = (int)q1; w.z = (int)q2;
      w.w = (int)((unsigned)vl | ((unsigned)v << 8));
      ((int4*)vpack)[dst] = w;
    }
    return;
  }

  int b = blk / NQ_, q = blk % NQ_;
  int l0 = 4 * q;
  int npos = (l0 + 4 <= L_) ? 4 : (L_ - l0);
  int alr = (blk < LU_) ? blk : -1;

  __shared__ float s_ur[KU_ * URP_];       // unit_repr padded (6100)
  __shared__ float s_cw[3 * DIM_ * CWP_];  // conv_w transposed (10980)
  __shared__ float s_aw[7 * KU_];          // 6 neighborhood aligner rows + align row
  __shared__ float s_kx[7 * DIM_];         // 6 ku rows + align ku row
  __shared__ float swr[4 * DIM_];          // conv outputs
  __shared__ float sclp[4 * KU_];          // char logits per position
  __shared__ float sctx[4 * KU_];          // ctx logits per position
  __shared__ float salg[KU_];              // align logits
  __shared__ float sls[9];                 // 8 pos logsumexps + align

  if (blk == 0 && t < B_) g_best[t * BEST_STRIDE] = 0ull;

  // --- P0: stage weights (float4 global) + aligner rows
  const float4* ur4 = (const float4*)unit_repr;
  for (int k = t; k < (KU_ * DIM_) / 4; k += 256) {
    float4 v = ur4[k];
    int i0 = 4 * k;
    s_ur[((i0 + 0) / DIM_) * URP_ + ((i0 + 0) % DIM_)] = v.x;
    s_ur[((i0 + 1) / DIM_) * URP_ + ((i0 + 1) % DIM_)] = v.y;
    s_ur[((i0 + 2) / DIM_) * URP_ + ((i0 + 2) % DIM_)] = v.z;
    s_ur[((i0 + 3) / DIM_) * URP_ + ((i0 + 3) % DIM_)] = v.w;
  }
  const float4* cw4 = (const float4*)conv_w;
  for (int k = t; k < (DIM_ * DIM_ * 3) / 4; k += 256) {
    float4 v = cw4[k];
    int i0 = 4 * k;
    float vv[4] = {v.x, v.y, v.z, v.w};
#pragma unroll
    for (int e = 0; e < 4; ++e) {
      int idx = i0 + e;
      int o = idx / (3 * DIM_), id = idx % (3 * DIM_);
      s_cw[id * CWP_ + o] = vv[e];
    }
  }
  for (int i = t; i < 7 * KU_; i += 256) {
    int m = i / KU_, k = i - m * KU_;
    float w = 0.f;
    if (m < 6) {
      int ld = l0 - 1 + m;
      if (ld >= 0 && ld < L_) {
        int u = uid[b * L_ + ld];
        w = aligner_w[u * KU_ + k];
      }
    } else if (alr >= 0) {
      w = aligner_w[alr * KU_ + k];
    }
    s_aw[i] = w;
  }
  __syncthreads();

  // --- P1: ku rows (420 outputs, 100 MACs)
  for (int idx = t; idx < 7 * DIM_; idx += 256) {
    int m = idx / DIM_, c = idx - m * DIM_;
    const float4* aw4 = (const float4*)&s_aw[m * KU_];
    float acc = 0.f;
    for (int k4 = 0; k4 < KU_ / 4; ++k4) {
      float4 a = aw4[k4];
      int k = 4 * k4;
      acc += a.x * s_ur[(k + 0) * URP_ + c];
      acc += a.y * s_ur[(k + 1) * URP_ + c];
      acc += a.z * s_ur[(k + 2) * URP_ + c];
      acc += a.w * s_ur[(k + 3) * URP_ + c];
    }
    s_kx[idx] = acc;
  }
  __syncthreads();

  // --- P2: conv (240) + char logits (400)
  for (int idx = t; idx < 240 + 4 * KU_; idx += 256) {
    if (idx < 240) {
      int p = idx / DIM_, o = idx - p * DIM_;
      const float4* x04 = (const float4*)&s_kx[(p + 0) * DIM_];
      const float4* x14 = (const float4*)&s_kx[(p + 1) * DIM_];
      const float4* x24 = (const float4*)&s_kx[(p + 2) * DIM_];
      float acc = conv_b[o];
      for (int i4 = 0; i4 < DIM_ / 4; ++i4) {
        float4 x0 = x04[i4], x1 = x14[i4], x2 = x24[i4];
        int i = 4 * i4;
        acc += x0.x * s_cw[((i + 0) * 3 + 0) * CWP_ + o];
        acc += x1.x * s_cw[((i + 0) * 3 + 1) * CWP_ + o];
        acc += x2.x * s_cw[((i + 0) * 3 + 2) * CWP_ + o];
        acc += x0.y * s_cw[((i + 1) * 3 + 0) * CWP_ + o];
        acc += x1.y * s_cw[((i + 1) * 3 + 1) * CWP_ + o];
        acc += x2.y * s_cw[((i + 1) * 3 + 2) * CWP_ + o];
        acc += x0.z * s_cw[((i + 2) * 3 + 0) * CWP_ + o];
        acc += x1.z * s_cw[((i + 2) * 3 + 1) * CWP_ + o];
        acc += x2.z * s_cw[((i + 2) * 3 + 2) * CWP_ + o];
        acc += x0.w * s_cw[((i + 3) * 3 + 0) * CWP_ + o];
        acc += x1.w * s_cw[((i + 3) * 3 + 1) * CWP_ + o];
        acc += x2.w * s_cw[((i + 3) * 3 + 2) * CWP_ + o];
      }
      swr[p * DIM_ + o] = acc;
    } else {
      int r = idx - 240;
      int p = r / KU_, j = r - p * KU_;
      const float4* kx4 = (const float4*)&s_kx[(p + 1) * DIM_];
      float acc = 0.f;
      for (int d4 = 0; d4 < DIM_ / 4; ++d4) {
        float4 x = kx4[d4];
        int d = 4 * d4;
        acc += x.x * s_ur[j * URP_ + d + 0];
        acc += x.y * s_ur[j * URP_ + d + 1];
        acc += x.z * s_ur[j * URP_ + d + 2];
        acc += x.w * s_ur[j * URP_ + d + 3];
      }
      sclp[r] = acc;
    }
  }
  __syncthreads();

  // --- P3: ctx logits (400) + align logits (100)
  for (int idx = t; idx < 4 * KU_ + KU_; idx += 256) {
    if (idx < 4 * KU_) {
      int p = idx / KU_, j = idx - p * KU_;
      const float4* w4 = (const float4*)&swr[p * DIM_];
      float acc = 0.f;
      for (int d4 = 0; d4 < DIM_ / 4; ++d4) {
        float4 x = w4[d4];
        int d = 4 * d4;
        acc += x.x * s_ur[j * URP_ + d + 0];
        acc += x.y * s_ur[j * URP_ + d + 1];
        acc += x.z * s_ur[j * URP_ + d + 2];
        acc += x.w * s_ur[j * URP_ + d + 3];
      }
      sctx[idx] = acc;
    } else {
      int j = idx - 4 * KU_;
      const float4* kx4 = (const float4*)&s_kx[6 * DIM_];
      float acc = 0.f;
      for (int d4 = 0; d4 < DIM_ / 4; ++d4) {
        float4 x = kx4[d4];
        int d = 4 * d4;
        acc += x.x * s_ur[j * URP_ + d + 0];
        acc += x.y * s_ur[j * URP_ + d + 1];
        acc += x.z * s_ur[j * URP_ + d + 2];
        acc += x.w * s_ur[j * URP_ + d + 3];
      }
      salg[j] = acc;
    }
  }
  __syncthreads();

  // --- P4: 9 logsumexp reductions
  {
    int g = t >> 5, lane = t & 31;
#pragma unroll
    for (int round = 0; round < 2; ++round) {
      int r = round * 8 + g;
      if (r < 9) {
        const float* arr = (r == 8) ? salg
                          : ((r & 1) ? &sctx[(r >> 1) * KU_] : &sclp[(r >> 1) * KU_]);
        float v1 = arr[lane];
        float v2 = arr[32 + lane];
        float v3 = arr[64 + lane];
        float v4 = (lane < KU_ - 96) ? arr[96 + lane] : -1e30f;
        float mx = fmaxf(fmaxf(v1, v2), fmaxf(v3, v4));
#pragma unroll
        for (int off = 16; off > 0; off >>= 1)
          mx = fmaxf(mx, __shfl_xor(mx, off));
        float s = expf(v1 - mx) + expf(v2 - mx) + expf(v3 - mx) +
                  ((lane < KU_ - 96) ? expf(v4 - mx) : 0.f);
#pragma unroll
        for (int off = 16; off > 0; off >>= 1)
          s += __shfl_xor(s, off);
        if (lane == 0) sls[r] = mx + logf(s);
      }
    }
  }
  __syncthreads();

  // --- P5: guarded outputs (pos_lp + 2*IDC: DP potential-transform operand)
  for (int idx = t; idx < 4 * KU_; idx += 256) {
    int p = idx / KU_, j = idx - p * KU_;
    if (p < npos) {
      float pos = (sclp[idx] - sls[2 * p]) + CTXW_ * (sctx[idx] - sls[2 * p + 1]);
      ws_plp[(b * L_ + l0 + p) * KU_ + j] = pos + 2.0f * IDC_;
    }
  }
  if (alr >= 0 && t < KU_)
    out_align[alr * KU_ + t] = expf(salg[t] - sls[8]);
}

// -------------------------------------------------------------------------
// dp4 core: ONE vocab (per-lane), FOUR consecutive start tiles m=0..3.
// Per column j: 7 ds_read_b64 fetch rows 0..13 once; 4 independent DP
// chains consume s[m+i-1]. Same potential-transform math as r3 (proven):
//   D[i] = max3(D[i-1]+s2, D[i], left), zero boundaries,
//   score(i) = D[i] + (len_b-i)*LOG_UNEXT - IDC*(i+VL).
#define CHAIN_(Dm, MOFF)                                                 \
  {                                                                      \
    float left = 0.f;                                                    \
    _Pragma("unroll")                                                    \
    for (int i = 1; i <= MAXVL_; ++i) {                                  \
      float nv = fmaxf(Dm[i - 1] + s[(i - 1) + (MOFF)],                  \
                       fmaxf(Dm[i], left));                              \
      Dm[i - 1] = left;                                                  \
      left = nv;                                                         \
    }                                                                    \
    Dm[MAXVL_] = left;                                                   \
  }

template<int VL>
__device__ __forceinline__ unsigned long long dp4_one(
    const float* __restrict__ sp,   // pair tile base
    unsigned q0, unsigned q1, unsigned q2,
    int imax0,                      // len_b - l0 (block-uniform)
    float lenLU,                    // len_b * LOG_UNEXT_ (block-uniform)
    int lbase0, int vid)
{
  float D0[MAXVL_ + 1], D1[MAXVL_ + 1], D2[MAXVL_ + 1], D3[MAXVL_ + 1];
#pragma unroll
  for (int i = 0; i <= MAXVL_; ++i) { D0[i] = 0.f; D1[i] = 0.f; D2[i] = 0.f; D3[i] = 0.f; }

#pragma unroll
  for (int j = 0; j < VL; ++j) {
    unsigned qq = (j < 4) ? q0 : ((j < 8) ? q1 : q2);
    int k2 = (int)((qq >> ((j & 3) * 8)) & 0xFFu) * 2;   // per-lane dword off
    const float* fb = sp + k2;
    float2 P0 = *(const float2*)(fb);
    float2 P1 = *(const float2*)(fb + S2P_);
    float2 P2 = *(const float2*)(fb + 2 * S2P_);
    float2 P3 = *(const float2*)(fb + 3 * S2P_);
    float2 P4 = *(const float2*)(fb + 4 * S2P_);
    float2 P5 = *(const float2*)(fb + 5 * S2P_);
    float2 P6 = *(const float2*)(fb + 6 * S2P_);
    float s[NROW_] = {P0.x, P0.y, P1.x, P1.y, P2.x, P2.y, P3.x, P3.y,
                      P4.x, P4.y, P5.x, P5.y, P6.x, P6.y};
    CHAIN_(D0, 0)
    CHAIN_(D1, 1)
    CHAIN_(D2, 2)
    CHAIN_(D3, 3)
  }

  unsigned long long bestKey = 0ull;
#pragma unroll
  for (int m = 0; m < 4; ++m) {
    const float* Dm = (m == 0) ? D0 : (m == 1) ? D1 : (m == 2) ? D2 : D3;
    int imax = imax0 - m;                       // block-uniform scalar
#pragma unroll
    for (int e = 0; e < NE_; ++e) {
      const int i = MIN_WL_ + e;
      if (i <= imax) {                          // scalar branch
        // (len_b-i)*LOG - IDC*(i+VL) = lenLU + i*(-LOG-IDC) - IDC*VL
        float cc = lenLU + (float)i * (-LOG_UNEXT_ - IDC_) - IDC_ * (float)VL;
        float sc = Dm[i] + cc;
        unsigned idx = (unsigned)(lbase0 + m * (NE_ * V_) + e * V_ + vid);
        unsigned u = __float_as_uint(sc);
        u = (u & 0x80000000u) ? ~u : (u | 0x80000000u);
        unsigned long long key =
            ((unsigned long long)u << 32) | (unsigned long long)(~idx);
        if (key > bestKey) bestKey = key;       // ties: smaller idx wins
      }
    }
  }
  return bestKey;
}

// -------------------------------------------------------------------------
// Kernel 2: dp4 — 208 blocks (b, l-quad) x 512 threads. Each block stages
// plp rows l0..l0+13 ONCE as 7 float2 pair-rows; each thread runs up to 4
// sorted vocabs (t, t+512, ...) x 4 start tiles. vlen-sorted vpack keeps
// the per-lane template if-chain near-wave-uniform (r3-proven pattern).
__global__ __launch_bounds__(512) void dp_kernel(
    const int* __restrict__ lengths,
    const float* __restrict__ ws_plp,       // (B*L, KU), pre-shifted by +2*IDC
    const int* __restrict__ vpack,          // (V, int4) sorted by vlen
    unsigned long long* __restrict__ g_best)
{
  int blk = blockIdx.x;
  int b = blk / NQ_, q = blk % NQ_;
  int l0 = 4 * q;
  int len_b = lengths[b];
  int imax0 = len_b - l0;
  if (imax0 < MIN_WL_) return;      // all 4 tiles non-viable (block-uniform)

  __shared__ float sp[7 * S2P_];    // 5824 B
  __shared__ unsigned long long swave[8];
  int t = threadIdx.x;

  // stage: sp[(r>>1)*S2P_ + 2k + (r&1)] = plp[b*L + l0 + r][k], r=0..13
  // (rows past L clamp within the buffer; garbage never reaches a capture:
  //  tile m captures i<=imax -> deepest row l0+m+i-1 <= len_b-1 < L)
  if (t < NROW_ * 25) {
    const float4* src4 = (const float4*)ws_plp;
    int r = t / 25, m4 = t - r * 25;
    int g = b * L_ + l0 + r;
    if (g > B_ * L_ - 1) g = B_ * L_ - 1;
    float4 v = src4[g * 25 + m4];
    float* dst = &sp[(r >> 1) * S2P_ + 8 * m4 + (r & 1)];
    dst[0] = v.x; dst[2] = v.y; dst[4] = v.z; dst[6] = v.w;
  }
  __syncthreads();

  float lenLU = (float)len_b * LOG_UNEXT_;
  int lbase0 = l0 * (NE_ * V_);
  const int4* vp4 = (const int4*)vpack;

  unsigned long long bestKey = 0ull;
  int4 wq = (t < V_) ? vp4[t] : make_int4(0, 0, 0, 0);
#pragma unroll 1
  for (int s4 = 0; s4 < 4; ++s4) {
    // prefetch next vocab entry: load flies under this iteration's DP
    int vn = t + (s4 + 1) * 512;
    int4 wqn = (s4 < 3 && vn < V_) ? vp4[vn] : make_int4(0, 0, 0, 0);
    unsigned q0 = (unsigned)wq.x, q1 = (unsigned)wq.y, q2 = (unsigned)wq.z;
    int vlen = (int)((unsigned)wq.w & 0xFFu);   // 0 when invalid -> skip
    int vid = (int)(((unsigned)wq.w) >> 8);
    unsigned long long kk = 0ull;
    if (vlen == 4)       kk = dp4_one<4>(sp, q0, q1, q2, imax0, lenLU, lbase0, vid);
    else if (vlen == 5)  kk = dp4_one<5>(sp, q0, q1, q2, imax0, lenLU, lbase0, vid);
    else if (vlen == 6)  kk = dp4_one<6>(sp, q0, q1, q2, imax0, lenLU, lbase0, vid);
    else if (vlen == 7)  kk = dp4_one<7>(sp, q0, q1, q2, imax0, lenLU, lbase0, vid);
    else if (vlen == 8)  kk = dp4_one<8>(sp, q0, q1, q2, imax0, lenLU, lbase0, vid);
    else if (vlen == 9)  kk = dp4_one<9>(sp, q0, q1, q2, imax0, lenLU, lbase0, vid);
    else if (vlen == 10) kk = dp4_one<10>(sp, q0, q1, q2, imax0, lenLU, lbase0, vid);
    if (kk > bestKey) bestKey = kk;
    wq = wqn;
  }

#pragma unroll
  for (int off = 32; off > 0; off >>= 1) {
    unsigned long long o = __shfl_down(bestKey, off);
    if (o > bestKey) bestKey = o;
  }
  int wid = t >> 6;
  if ((t & 63) == 0) swave[wid] = bestKey;
  __syncthreads();
  if (t == 0) {
    unsigned long long k0 = swave[0];
    for (int w = 1; w < 8; ++w)
      if (swave[w] > k0) k0 = swave[w];
    atomicMax(g_best + (size_t)b * BEST_STRIDE, k0);
  }
}

// -------------------------------------------------------------------------
// Kernel 3: decode. Separate launch = implicit device-wide fence
// (measured r4->r5: extra dispatch costs only ~0.2us).
__global__ void decode_kernel(const unsigned long long* __restrict__ g_best,
                              float* __restrict__ out)
{
  int t = threadIdx.x;
  if (t < B_) {
    unsigned long long key = g_best[t * BEST_STRIDE];
    unsigned int u = (unsigned int)(key >> 32);
    unsigned int idx = ~((unsigned int)(key & 0xFFFFFFFFull));
    unsigned int bits = (u & 0x80000000u) ? (u & 0x7FFFFFFFu) : ~u;
    float val = __uint_as_float(bits);
    int start = (int)(idx / (NE_ * V_));
    int rem = (int)(idx % (NE_ * V_));
    int e = rem / V_;
    int vv = rem % V_;
    out[t] = (float)start;
    out[B_ + t] = (float)(start + MIN_WL_ + e - 1);
    out[2 * B_ + t] = val;
    out[3 * B_ + t] = (float)vv;
  }
}

// -------------------------------------------------------------------------
extern "C" void kernel_launch(void* const* d_in, const int* in_sizes, int n_in,
                              void* d_out, int out_size, void* d_ws, size_t ws_size,
                              hipStream_t stream)
{
  const int* uid            = (const int*)d_in[0];
  const int* lengths        = (const int*)d_in[1];
  const float* unit_repr    = (const float*)d_in[2];
  const float* aligner_w    = (const float*)d_in[3];
  const float* conv_w       = (const float*)d_in[4];
  const float* conv_b       = (const float*)d_in[5];
  const int* vocab_ids      = (const int*)d_in[6];
  const int* vocab_lengths  = (const int*)d_in[7];
  float* out = (float*)d_out;
  float* ws_f = (float*)d_ws;
  unsigned long long* g_best =
      (unsigned long long*)((char*)d_ws + WS_BEST_BYTES);
  int* vpack = (int*)((char*)d_ws + WS_VPACK_BYTES);

  ctx_kernel<<<B_ * NQ_ + 1, 256, 0, stream>>>(uid, unit_repr, aligner_w,
                                               conv_w, conv_b, vocab_ids,
                                               vocab_lengths, ws_f + WS_PLP,
                                               out + 4 * B_, g_best, vpack);
  dp_kernel<<<B_ * NQ_, 512, 0, stream>>>(lengths, ws_f + WS_PLP, vpack,
                                          g_best);
  decode_kernel<<<1, 64, 0, stream>>>(g_best, out);
}